// Round 13
// baseline (344.556 us; speedup 1.0000x reference)
//
#include <hip/hip_runtime.h>
#include <cstdint>
#include <cstddef>

#define B_  4
#define S_  2048
#define D_  1024
#define H_  16
#define HD_ 64
#define M_  (B_ * S_)   // 8192 rows

#define QB_ 8           // blocks per (b,h) sequence
#define QC_ 16          // chunks per block (one wave each)
#define CLq 16          // chunk length; QB_*QC_*CLq == S_

#define FPAD 16         // flag padding: 16 u32 = 64 B = one cacheline per flag

typedef __bf16 bf16_t;
typedef bf16_t bf16x8 __attribute__((ext_vector_type(8)));
typedef bf16_t bf16x4 __attribute__((ext_vector_type(4)));
typedef float  floatx4 __attribute__((ext_vector_type(4)));

// ---------------------------------------------------------------------------
// async 16B global -> LDS copy (gfx950). LDS dest is wave-uniform base +
// lane*16 (m104/m108); all uses below pass lds = base + lane*16 exactly.
// ---------------------------------------------------------------------------
__device__ __forceinline__ void async_copy16(const void* gmem, void* lds) {
  __builtin_amdgcn_global_load_lds(
      (__attribute__((address_space(1))) void*)const_cast<void*>(gmem),
      (__attribute__((address_space(3))) void*)lds,
      16, 0, 0);
}

// ---------------------------------------------------------------------------
// Fused prologue: weight fp32->bf16 cast (4M elems) + token-shift mix (8M).
// x4 vectorized (float4 loads, bf16x4 stores) per G13.
// ---------------------------------------------------------------------------
__global__ void pre_kernel(const float* __restrict__ w0, const float* __restrict__ w1,
                           const float* __restrict__ w2, const float* __restrict__ w3,
                           bf16_t* __restrict__ wout,
                           const float* __restrict__ x,
                           const float* __restrict__ tmr, const float* __restrict__ tmk,
                           const float* __restrict__ tmv,
                           bf16_t* __restrict__ xr, bf16_t* __restrict__ xk,
                           bf16_t* __restrict__ xv) {
  const int WQ = 1 << 18;                       // 256K float4-groups per weight
  int gid = blockIdx.x * blockDim.x + threadIdx.x;   // 0 .. 3M-1
  if (gid < 4 * WQ) {
    int sel = gid >> 18;
    const float* src = sel == 0 ? w0 : sel == 1 ? w1 : sel == 2 ? w2 : w3;
    int e = (gid & (WQ - 1)) << 2;
    const float4 v = *(const float4*)(src + e);
    bf16x4 o = { (bf16_t)v.x, (bf16_t)v.y, (bf16_t)v.z, (bf16_t)v.w };
    *(bf16x4*)(wout + ((size_t)gid << 2)) = o;
  } else {
    int g2 = gid - 4 * WQ;                      // 0 .. 2M-1
    size_t idx = (size_t)g2 << 2;               // element index, 4-aligned
    int d = (int)(idx & (D_ - 1));
    int t = (int)((idx >> 10) & (S_ - 1));
    float4 xc = *(const float4*)(x + idx);
    float4 xp = make_float4(0.f, 0.f, 0.f, 0.f);
    if (t != 0) xp = *(const float4*)(x + idx - D_);
    float4 mr = *(const float4*)(tmr + d);
    float4 mk = *(const float4*)(tmk + d);
    float4 mv = *(const float4*)(tmv + d);
    bf16x4 orv = { (bf16_t)(xc.x * mr.x + xp.x * (1.f - mr.x)),
                   (bf16_t)(xc.y * mr.y + xp.y * (1.f - mr.y)),
                   (bf16_t)(xc.z * mr.z + xp.z * (1.f - mr.z)),
                   (bf16_t)(xc.w * mr.w + xp.w * (1.f - mr.w)) };
    bf16x4 okv = { (bf16_t)(xc.x * mk.x + xp.x * (1.f - mk.x)),
                   (bf16_t)(xc.y * mk.y + xp.y * (1.f - mk.y)),
                   (bf16_t)(xc.z * mk.z + xp.z * (1.f - mk.z)),
                   (bf16_t)(xc.w * mk.w + xp.w * (1.f - mk.w)) };
    bf16x4 ovv = { (bf16_t)(xc.x * mv.x + xp.x * (1.f - mv.x)),
                   (bf16_t)(xc.y * mv.y + xp.y * (1.f - mv.y)),
                   (bf16_t)(xc.z * mv.z + xp.z * (1.f - mv.z)),
                   (bf16_t)(xc.w * mv.w + xp.w * (1.f - mv.w)) };
    *(bf16x4*)(xr + idx) = orv;
    *(bf16x4*)(xk + idx) = okv;
    *(bf16x4*)(xv + idx) = ovv;
  }
}

// ---------------------------------------------------------------------------
// r10 GEMM core (unchanged): T3 fine-phase + T4 counted-vmcnt + T5 setprio.
// ---------------------------------------------------------------------------
#define STG(kt, la, lb, p) do {                                            \
    const char* _ga = Abase + (size_t)(kt) * 128;                          \
    const char* _gb = Bbase + (size_t)(kt) * 128;                          \
    async_copy16(_ga + (size_t)(((p) * 2 + 0) * 64 + r8) * 2048 + cbs,     \
                 (la) + ((p) * 2 + 0) * 8192 + tid * 16);                  \
    async_copy16(_ga + (size_t)(((p) * 2 + 1) * 64 + r8) * 2048 + cbs,     \
                 (la) + ((p) * 2 + 1) * 8192 + tid * 16);                  \
    async_copy16(_gb + (size_t)((p) * 64 + r8) * 2048 + cbs,               \
                 (lb) + (p) * 8192 + tid * 16);                            \
  } while (0)

#define PH1(la, lb, STMT) do {                                             \
    _Pragma("unroll")                                                      \
    for (int _j = 0; _j < 4; ++_j) {                                       \
      const char* _rb = (lb) + (wn * 64 + _j * 16 + l15) * 128;            \
      bfr[_j][0] = *(const bf16x8*)(_rb + ((quad * 16) ^ swz));            \
      bfr[_j][1] = *(const bf16x8*)(_rb + ((64 + quad * 16) ^ swz));       \
    }                                                                      \
    _Pragma("unroll")                                                      \
    for (int _i = 0; _i < 2; ++_i) {                                       \
      const char* _ra = (la) + (wm * 64 + _i * 16 + l15) * 128;            \
      afr[_i][0] = *(const bf16x8*)(_ra + ((quad * 16) ^ swz));            \
      afr[_i][1] = *(const bf16x8*)(_ra + ((64 + quad * 16) ^ swz));       \
    }                                                                      \
    STMT;                                                                  \
    asm volatile("s_waitcnt lgkmcnt(0)" ::: "memory");                     \
    __builtin_amdgcn_sched_barrier(0);                                     \
    __builtin_amdgcn_s_setprio(1);                                         \
    _Pragma("unroll")                                                      \
    for (int _k = 0; _k < 2; ++_k)                                         \
      _Pragma("unroll")                                                    \
      for (int _i = 0; _i < 2; ++_i)                                       \
        _Pragma("unroll")                                                  \
        for (int _j = 0; _j < 4; ++_j)                                     \
          acc[_i][_j] = __builtin_amdgcn_mfma_f32_16x16x32_bf16(           \
              afr[_i][_k], bfr[_j][_k], acc[_i][_j], 0, 0, 0);             \
    __builtin_amdgcn_s_setprio(0);                                         \
  } while (0)

#define PH2(la, STMT) do {                                                 \
    _Pragma("unroll")                                                      \
    for (int _i = 0; _i < 2; ++_i) {                                       \
      const char* _ra = (la) + (wm * 64 + (2 + _i) * 16 + l15) * 128;      \
      afr[_i][0] = *(const bf16x8*)(_ra + ((quad * 16) ^ swz));            \
      afr[_i][1] = *(const bf16x8*)(_ra + ((64 + quad * 16) ^ swz));       \
    }                                                                      \
    STMT;                                                                  \
    asm volatile("s_waitcnt lgkmcnt(0)" ::: "memory");                     \
    __builtin_amdgcn_sched_barrier(0);                                     \
    __builtin_amdgcn_s_setprio(1);                                         \
    _Pragma("unroll")                                                      \
    for (int _k = 0; _k < 2; ++_k)                                         \
      _Pragma("unroll")                                                    \
      for (int _i = 0; _i < 2; ++_i)                                       \
        _Pragma("unroll")                                                  \
        for (int _j = 0; _j < 4; ++_j)                                     \
          acc[2 + _i][_j] = __builtin_amdgcn_mfma_f32_16x16x32_bf16(       \
              afr[_i][_k], bfr[_j][_k], acc[2 + _i][_j], 0, 0, 0);         \
    __builtin_amdgcn_s_setprio(0);                                         \
  } while (0)

#define FENCE_BAR(N) do {                                                  \
    asm volatile("s_waitcnt vmcnt(" #N ")" ::: "memory");                  \
    __builtin_amdgcn_s_barrier();                                          \
    asm volatile("" ::: "memory");                                         \
  } while (0)

template <typename CT>
__device__ __forceinline__ void gemm_core(const bf16_t* __restrict__ A,
                                          const bf16_t* __restrict__ Bw,
                                          CT* __restrict__ C, int m0, int n0) {
  __shared__ __align__(16) bf16_t As[3][256][64];   // 96 KiB
  __shared__ __align__(16) bf16_t Bs[3][128][64];   // 48 KiB

  const int tid  = threadIdx.x;
  const int lane = tid & 63;
  const int wave = tid >> 6;
  const int wm   = wave >> 1;
  const int wn   = wave & 1;
  const int l15  = lane & 15;
  const int quad = lane >> 4;
  const int r8   = tid >> 3;
  const int cbs  = (((tid & 7) ^ (r8 & 7)) << 4);
  const int swz  = (l15 & 7) << 4;

  const char* Abase = (const char*)(A + (size_t)m0 * D_);
  const char* Bbase = (const char*)(Bw + (size_t)n0 * D_);

  char* const a0 = (char*)&As[0][0][0];
  char* const a1 = a0 + 32768;
  char* const a2 = a1 + 32768;
  char* const b0 = (char*)&Bs[0][0][0];
  char* const b1 = b0 + 16384;
  char* const b2 = b1 + 16384;

  floatx4 acc[4][4] = {};
  bf16x8 afr[2][2], bfr[4][2];

  STG(0, a0, b0, 0); STG(0, a0, b0, 1);
  STG(1, a1, b1, 0); STG(1, a1, b1, 1);
  FENCE_BAR(6);

  char *aC = a0, *aN = a1, *aF = a2;
  char *bC = b0, *bN = b1, *bF = b2;

#pragma unroll 1
  for (int t = 0; t < 14; ++t) {
    PH1(aC, bC, STG(t + 2, aF, bF, 0));
    PH2(aC,     STG(t + 2, aF, bF, 1));
    FENCE_BAR(6);
    char* x;
    x = aC; aC = aN; aN = aF; aF = x;
    x = bC; bC = bN; bN = bF; bF = x;
  }
  PH1(aC, bC, (void)0);
  PH2(aC,     (void)0);
  FENCE_BAR(0);
  PH1(aN, bN, (void)0);
  PH2(aN,     (void)0);

#pragma unroll
  for (int i = 0; i < 4; ++i) {
#pragma unroll
    for (int j = 0; j < 4; ++j) {
      int row = m0 + wm * 64 + i * 16 + quad * 4;
      int col = n0 + wn * 64 + j * 16 + l15;
      CT* Cp = C + (size_t)row * D_ + col;
#pragma unroll
      for (int r = 0; r < 4; ++r)
        Cp[(size_t)r * D_] = (CT)acc[i][j][r];
    }
  }
}

__global__ __launch_bounds__(512, 2)
void gemm3(const bf16_t* __restrict__ xr, const bf16_t* __restrict__ xk,
           const bf16_t* __restrict__ xv, const bf16_t* __restrict__ Wall,
           bf16_t* __restrict__ rbuf, bf16_t* __restrict__ kbuf, bf16_t* __restrict__ vbuf) {
  const int flat = blockIdx.x;                  // 0..767
  const int idx  = (flat & 7) * 96 + (flat >> 3);
  const int proj = idx >> 8;
  const int tt   = idx & 255;
  const int mb   = tt >> 3;
  const int nb   = tt & 7;
  const bf16_t* A  = (proj == 0) ? xr : (proj == 1) ? xk : xv;
  const bf16_t* Bw = Wall + (size_t)proj * (1 << 20);
  bf16_t* C = (proj == 0) ? rbuf : (proj == 1) ? kbuf : vbuf;
  gemm_core<bf16_t>(A, Bw, C, mb * 256, nb * 128);
}

__global__ __launch_bounds__(512, 2)
void gemm_bt(const bf16_t* __restrict__ A, const bf16_t* __restrict__ Bw,
             float* __restrict__ C) {
  const int flat = blockIdx.x;                  // 0..255
  const int idx  = (flat & 7) * 32 + (flat >> 3);
  const int mb   = idx >> 3;
  const int nb   = idx & 7;
  gemm_core<float>(A, Bw, C, mb * 256, nb * 128);
}

// ---------------------------------------------------------------------------
// bf16 chunk staging for CL=16: 2 wave-instrs stage a 16-t x 64-ch tile (2KB).
// ---------------------------------------------------------------------------
__device__ __forceinline__ void stage_chunk16(const char* gsrc, char* lds, int lane) {
  const int row = lane >> 3;            // 0..7 within group
  const int cb  = (lane & 7) * 16;
#pragma unroll
  for (int i = 0; i < 2; ++i) {
    size_t go = (size_t)(i * 8 + row) * (D_ * 2) + cb;
    async_copy16(gsrc + go, lds + i * 1024 + lane * 16);
  }
}

// ---------------------------------------------------------------------------
// r21: union of three verified pieces (never combined before):
//   * 512 blocks (QB=8, CLq=16): serial chains halved AND grid finally
//     supplies 2 blocks/CU (r20's fatal flaw: 256 blocks on 256 CUs can
//     never exceed 1 block/CU no matter the LDS).
//   * r20's diet: k-only LDS (32K), o2 written back into consumed kS slots,
//     (1024,4) bound -> compiler lands VGPR ~32 naturally (r20 measured);
//     32 <= 64 means HW grants 8 waves/SIMD. LDS ~49K -> 2 blocks/CU.
//   * r19's padded flags (64B/flag) + s_sleep(32): the QB=8 poll-contention
//     that sank r17 (146us) was measured UNPADDED with spilled regs.
//   All 512 blocks co-resident (2/CU x 256) -> spins deadlock-free.
// Diagnostic: Occupancy must rise to ~75-85%; if yes but dur >= 60us,
// padded polling still saturates at 512 pollers -> tree-combine next.
// ---------------------------------------------------------------------------
__global__ __launch_bounds__(1024, 4)
void wkv_gn(const bf16_t* __restrict__ rbuf, const bf16_t* __restrict__ kbuf,
            const bf16_t* __restrict__ vbuf,
            const float* __restrict__ time_decay, const float* __restrict__ time_first,
            const float* __restrict__ gamma, const float* __restrict__ beta,
            float* __restrict__ Gtot, float* __restrict__ Atot, float* __restrict__ Btot,
            unsigned* __restrict__ flagG, unsigned* __restrict__ flagT,
            unsigned* __restrict__ cnt, float* __restrict__ psum, float* __restrict__ psq,
            bf16_t* __restrict__ normed) {
  __shared__ __align__(16) bf16_t kS[QC_][CLq * 64];   // 32 KB (o2 reuses it)
  __shared__ float Gs[QC_][64];                        // 4 KB
  __shared__ float As_[QC_][64];                       // 4 KB
  __shared__ float Bs_[QC_][64];                       // 4 KB
  __shared__ float predA[QB_ - 1][64];                 // 1.75 KB
  __shared__ float predB[QB_ - 1][64];                 // 1.75 KB
  __shared__ float redS[QC_], redQ[QC_];
  __shared__ float statsLds[2];

  const int blk  = blockIdx.x;      // 0..511
  const int bh   = blk & 63;
  const int q    = blk >> 6;        // 0..7
  const int tid  = threadIdx.x;
  const int lc   = tid >> 6;        // 0..15 local chunk (wave)
  const int lane = tid & 63;
  const int b = bh >> 4, h = bh & 15;
  const int c = h * HD_ + lane;
  const float w = -__expf(time_decay[c]);
  const float u = time_first[c];
  const float wCL  = w * (float)CLq;           // 16-step hop
  const float wBLK = w * (float)(QC_ * CLq);   // 256-step hop

  const int chunk = q * QC_ + lc;   // 0..127 global chunk
  const size_t sbase = ((size_t)b * S_ + (size_t)chunk * CLq) * D_ + h * HD_;
  const size_t gbase = sbase + lane;
  const bf16_t* vg = vbuf + gbase;
  const bf16_t* rg = rbuf + gbase;
  const int pidx = bh * QB_;        // flag/payload base for this bh

  // ---- stage k tile (coalesced, reused by all 3 phases; o2 reuses slots) ----
  stage_chunk16((const char*)(kbuf + sbase), (char*)&kS[lc][0], lane);
  __builtin_amdgcn_s_waitcnt(0);    // own-wave loads only

  // ---- Phase A: chunk-local b-scan from -inf (k from LDS) ----
  {
    float g = -1e38f;
#pragma unroll
    for (int t = 0; t < CLq; ++t) {
      float kt = (float)kS[lc][t * 64 + lane];
      float ww = g + w;
      float d2 = ww - kt;
      float em = __expf(-fabsf(d2));
      float e1b = (d2 >= 0.0f) ? 1.0f : em;
      float e2b = (d2 >= 0.0f) ? em : 1.0f;
      g = fmaxf(ww, kt) + __logf(e1b + e2b + 1e-8f);
    }
    Gs[lc][lane] = g;
  }
  __syncthreads();

  // exclusive local prefix P; wave15 publishes block total
  float P = -1e38f;
  for (int cc = 0; cc < lc; ++cc) {
    float gv = Gs[cc][lane];
    float b1 = P + wCL;
    float dd = b1 - gv;
    float em = __expf(-fabsf(dd));
    P = fmaxf(b1, gv) + __logf(1.0f + em);
  }
  if (lc == QC_ - 1) {
    float gv = Gs[QC_ - 1][lane];
    float b1 = P + wCL;
    float dd = b1 - gv;
    float em = __expf(-fabsf(dd));
    float gt = fmaxf(b1, gv) + __logf(1.0f + em);
    *((volatile float*)(Gtot + (pidx + q) * 64 + lane)) = gt;
    __threadfence();
    if (lane == 0)
      __hip_atomic_store(&flagG[(pidx + q) * FPAD], 1u, __ATOMIC_RELEASE, __HIP_MEMORY_SCOPE_AGENT);
  }

  // gather predecessor G totals: wave0 only; lane0 polls; coalesced payload
  if (lc == 0) {
    for (int j = 0; j < q; ++j) {
      if (lane == 0)
        while (__hip_atomic_load(&flagG[(pidx + j) * FPAD], __ATOMIC_ACQUIRE, __HIP_MEMORY_SCOPE_AGENT) == 0u)
          __builtin_amdgcn_s_sleep(32);
      predA[j][lane] = *((volatile const float*)(Gtot + (pidx + j) * 64 + lane));
    }
  }
  __syncthreads();

  float b_in = -1e38f;
  for (int j = 0; j < q; ++j) {
    float gt = predA[j][lane];
    float b1 = b_in + wBLK;
    float dd = b1 - gt;
    float em = __expf(-fabsf(dd));
    b_in = fmaxf(b1, gt) + __logf(1.0f + em);
  }
  float bst_in;
  {
    float b1 = b_in + wCL * (float)lc;
    float dd = b1 - P;
    float em = __expf(-fabsf(dd));
    bst_in = fmaxf(b1, P) + __logf(1.0f + em);
  }

  // ---- Phase B: a-transfer scan (k from LDS, v strided global) ----
  {
    float a = 0.0f, Ap = 1.0f;
    float bst = bst_in;
#pragma unroll 4
    for (int t = 0; t < CLq; ++t) {
      float kt = (float)kS[lc][t * 64 + lane];
      float vt = (float)vg[(size_t)t * D_];
      float ww = bst + w;
      float d2 = ww - kt;
      float em = __expf(-fabsf(d2));
      float e1b = (d2 >= 0.0f) ? 1.0f : em;
      float e2b = (d2 >= 0.0f) ? em : 1.0f;
      a  = e1b * a + e2b * vt;
      Ap = Ap * e1b;
      bst = fmaxf(ww, kt) + __logf(e1b + e2b + 1e-8f);
    }
    As_[lc][lane] = Ap;
    Bs_[lc][lane] = a;
  }
  __syncthreads();

  float Aex = 1.0f, Bex = 0.0f;
  for (int cc = 0; cc < lc; ++cc) {
    float Ac = As_[cc][lane], Bc = Bs_[cc][lane];
    Aex = Ac * Aex;
    Bex = Ac * Bex + Bc;
  }
  if (lc == QC_ - 1) {
    float Ac = As_[QC_ - 1][lane], Bc = Bs_[QC_ - 1][lane];
    float At = Ac * Aex;
    float Bt = Ac * Bex + Bc;
    *((volatile float*)(Atot + (pidx + q) * 64 + lane)) = At;
    *((volatile float*)(Btot + (pidx + q) * 64 + lane)) = Bt;
    __threadfence();
    if (lane == 0)
      __hip_atomic_store(&flagT[(pidx + q) * FPAD], 1u, __ATOMIC_RELEASE, __HIP_MEMORY_SCOPE_AGENT);
  }

  if (lc == 0) {
    for (int j = 0; j < q; ++j) {
      if (lane == 0)
        while (__hip_atomic_load(&flagT[(pidx + j) * FPAD], __ATOMIC_ACQUIRE, __HIP_MEMORY_SCOPE_AGENT) == 0u)
          __builtin_amdgcn_s_sleep(32);
      predA[j][lane] = *((volatile const float*)(Atot + (pidx + j) * 64 + lane));
      predB[j][lane] = *((volatile const float*)(Btot + (pidx + j) * 64 + lane));
    }
  }
  __syncthreads();

  float a_in = 0.0f;
  for (int j = 0; j < q; ++j)
    a_in = predA[j][lane] * a_in + predB[j][lane];
  const float a0 = Aex * a_in + Bex;

  // ---- Phase C: exact reference steps; o2 -> kS slot (bf16); GN partials ----
  {
    float a = a0, bst = bst_in;
    float sum = 0.0f, sq = 0.0f;
#pragma unroll 4
    for (int t = 0; t < CLq; ++t) {
      float kt = (float)kS[lc][t * 64 + lane];
      float vt = (float)vg[(size_t)t * D_];
      float rt = (float)rg[(size_t)t * D_];
      float wk = kt + u;
      float d1 = bst - wk;
      float em1 = __expf(-fabsf(d1));
      float e1 = (d1 >= 0.0f) ? 1.0f : em1;
      float e2 = (d1 >= 0.0f) ? em1 : 1.0f;
      float out = __fdividef(e1 * a + e2 * vt, e1 + e2 + 1e-8f);

      float ww = bst + w;
      float d2 = ww - kt;
      float em2 = __expf(-fabsf(d2));
      float e1b = (d2 >= 0.0f) ? 1.0f : em2;
      float e2b = (d2 >= 0.0f) ? em2 : 1.0f;
      a   = e1b * a + e2b * vt;
      bst = fmaxf(ww, kt) + __logf(e1b + e2b + 1e-8f);

      float sig = __fdividef(1.0f, 1.0f + __expf(-rt));
      float o = sig * out;
      kS[lc][t * 64 + lane] = (bf16_t)o;   // overwrite consumed k slot
      sum += o; sq += o * o;
    }
#pragma unroll
    for (int off = 32; off > 0; off >>= 1) {
      sum += __shfl_down(sum, off);
      sq  += __shfl_down(sq, off);
    }
    if (lane == 0) { redS[lc] = sum; redQ[lc] = sq; }
  }
  __syncthreads();
  if (tid == 0) {
    float s = 0.0f, qq = 0.0f;
#pragma unroll
    for (int i = 0; i < QC_; ++i) { s += redS[i]; qq += redQ[i]; }
    atomicAdd(&psum[bh * FPAD], s);
    atomicAdd(&psq[bh * FPAD], qq);
    __threadfence();
    atomicAdd(&cnt[bh * FPAD], 1u);
    while (__hip_atomic_load(&cnt[bh * FPAD], __ATOMIC_ACQUIRE, __HIP_MEMORY_SCOPE_AGENT) < (unsigned)QB_)
      __builtin_amdgcn_s_sleep(32);
    float sA = *((volatile const float*)&psum[bh * FPAD]);
    float qA = *((volatile const float*)&psq[bh * FPAD]);
    const float n = (float)(S_ * HD_);
    float mean = sA / n;
    float var  = qA / n - mean * mean;
    statsLds[0] = mean;
    statsLds[1] = rsqrtf(var + 1e-5f);
  }
  __syncthreads();

  // ---- Phase D: GroupNorm apply (o2 from kS) ----
  {
    const float mean = statsLds[0];
    const float gm   = gamma[c] * statsLds[1];
    const float bt   = beta[c];
    bf16_t* og = normed + gbase;
#pragma unroll 4
    for (int t = 0; t < CLq; ++t)
      og[(size_t)t * D_] = (bf16_t)(((float)kS[lc][t * 64 + lane] - mean) * gm + bt);
  }
}

// ---------------------------------------------------------------------------
extern "C" void kernel_launch(void* const* d_in, const int* in_sizes, int n_in,
                              void* d_out, int out_size, void* d_ws, size_t ws_size,
                              hipStream_t stream) {
  const float* x     = (const float*)d_in[0];
  const float* tmr   = (const float*)d_in[1];
  const float* tmk   = (const float*)d_in[2];
  const float* tmv   = (const float*)d_in[3];
  const float* Wr    = (const float*)d_in[4];
  const float* Wk    = (const float*)d_in[5];
  const float* Wv    = (const float*)d_in[6];
  const float* Wo    = (const float*)d_in[7];
  const float* td    = (const float*)d_in[8];
  const float* tf    = (const float*)d_in[9];
  const float* gamma = (const float*)d_in[10];
  const float* beta  = (const float*)d_in[11];

  char* ws = (char*)d_ws;
  const size_t MB = 1024 * 1024;
  bf16_t* W_bf    = (bf16_t*)(ws + 0 * MB);    // Wr,Wk,Wv,Wo bf16, 8 MB
  bf16_t* Wo_bf   = (bf16_t*)(ws + 6 * MB);
  bf16_t* xr      = (bf16_t*)(ws + 8 * MB);    // 16 MB each
  bf16_t* xk      = (bf16_t*)(ws + 24 * MB);
  bf16_t* xv      = (bf16_t*)(ws + 40 * MB);
  // scan sync/scratch in dead xk space (28 MB +); zeroed AFTER gemm3.
  // All flags/counters cacheline-padded (FPAD=16 u32 = 64 B).
  unsigned* flagG = (unsigned*)(ws + 28 * MB);          // 512*64B = 32 KB
  unsigned* flagT = (unsigned*)(ws + 28 * MB + 32768);  // 32 KB
  unsigned* cnt   = (unsigned*)(ws + 28 * MB + 65536);  // 64*64B = 4 KB
  float*    psum  = (float*)(ws + 28 * MB + 69632);     // 4 KB (padded)
  float*    psq   = (float*)(ws + 28 * MB + 73728);     // 4 KB (padded)
  float*    Gtot  = (float*)(ws + 28 * MB + 128 * 1024); // 512*64 f32 = 128KB each
  float*    Atot  = Gtot + 512 * 64;
  float*    Btot  = Atot + 512 * 64;
  bf16_t* rbuf    = (bf16_t*)(ws + 56 * MB);   // 16 MB each, bf16
  bf16_t* kbuf    = (bf16_t*)(ws + 72 * MB);
  bf16_t* vbuf    = (bf16_t*)(ws + 88 * MB);
  bf16_t* normed  = xr;                        // xr dead after gemm3

  float* outp = (float*)d_out;

  pre_kernel<<<(3 * 1024 * 1024) / 256, 256, 0, stream>>>(
      Wr, Wk, Wv, Wo, W_bf, x, tmr, tmk, tmv, xr, xk, xv);

  gemm3<<<768, 512, 0, stream>>>(xr, xk, xv, W_bf, rbuf, kbuf, vbuf);

  hipMemsetAsync(ws + 28 * MB, 0, 81920, stream);  // padded flags/cnt/psum/psq

  wkv_gn<<<512, 1024, 0, stream>>>(rbuf, kbuf, vbuf, td, tf, gamma, beta,
                                   Gtot, Atot, Btot, flagG, flagT, cnt,
                                   psum, psq, normed);

  gemm_bt<<<256, 512, 0, stream>>>(normed, Wo_bf, outp);
}

// Round 14
// 246.115 us; speedup vs baseline: 1.4000x; 1.4000x over previous
//
#include <hip/hip_runtime.h>
#include <cstdint>
#include <cstddef>

#define B_  4
#define S_  2048
#define D_  1024
#define H_  16
#define HD_ 64
#define M_  (B_ * S_)   // 8192 rows

#define QB_ 4           // blocks per (b,h) sequence
#define QC_ 16          // chunks per block (one wave each)
#define CLq 32          // chunk length; QB_*QC_*CLq == S_

#define FPAD 16         // flag padding: 16 u32 = 64 B = one cacheline per flag

typedef __bf16 bf16_t;
typedef bf16_t bf16x8 __attribute__((ext_vector_type(8)));
typedef bf16_t bf16x4 __attribute__((ext_vector_type(4)));
typedef float  floatx4 __attribute__((ext_vector_type(4)));

// ---------------------------------------------------------------------------
// async 16B global -> LDS copy (gfx950). LDS dest is wave-uniform base +
// lane*16 (m104/m108); all uses below pass lds = base + lane*16 exactly.
// ---------------------------------------------------------------------------
__device__ __forceinline__ void async_copy16(const void* gmem, void* lds) {
  __builtin_amdgcn_global_load_lds(
      (__attribute__((address_space(1))) void*)const_cast<void*>(gmem),
      (__attribute__((address_space(3))) void*)lds,
      16, 0, 0);
}

// ---------------------------------------------------------------------------
// Fused prologue: weight fp32->bf16 cast (4M elems) + token-shift mix (8M).
// x4 vectorized (float4 loads, bf16x4 stores) per G13.
// ---------------------------------------------------------------------------
__global__ void pre_kernel(const float* __restrict__ w0, const float* __restrict__ w1,
                           const float* __restrict__ w2, const float* __restrict__ w3,
                           bf16_t* __restrict__ wout,
                           const float* __restrict__ x,
                           const float* __restrict__ tmr, const float* __restrict__ tmk,
                           const float* __restrict__ tmv,
                           bf16_t* __restrict__ xr, bf16_t* __restrict__ xk,
                           bf16_t* __restrict__ xv) {
  const int WQ = 1 << 18;                       // 256K float4-groups per weight
  int gid = blockIdx.x * blockDim.x + threadIdx.x;   // 0 .. 3M-1
  if (gid < 4 * WQ) {
    int sel = gid >> 18;
    const float* src = sel == 0 ? w0 : sel == 1 ? w1 : sel == 2 ? w2 : w3;
    int e = (gid & (WQ - 1)) << 2;
    const float4 v = *(const float4*)(src + e);
    bf16x4 o = { (bf16_t)v.x, (bf16_t)v.y, (bf16_t)v.z, (bf16_t)v.w };
    *(bf16x4*)(wout + ((size_t)gid << 2)) = o;
  } else {
    int g2 = gid - 4 * WQ;                      // 0 .. 2M-1
    size_t idx = (size_t)g2 << 2;               // element index, 4-aligned
    int d = (int)(idx & (D_ - 1));
    int t = (int)((idx >> 10) & (S_ - 1));
    float4 xc = *(const float4*)(x + idx);
    float4 xp = make_float4(0.f, 0.f, 0.f, 0.f);
    if (t != 0) xp = *(const float4*)(x + idx - D_);
    float4 mr = *(const float4*)(tmr + d);
    float4 mk = *(const float4*)(tmk + d);
    float4 mv = *(const float4*)(tmv + d);
    bf16x4 orv = { (bf16_t)(xc.x * mr.x + xp.x * (1.f - mr.x)),
                   (bf16_t)(xc.y * mr.y + xp.y * (1.f - mr.y)),
                   (bf16_t)(xc.z * mr.z + xp.z * (1.f - mr.z)),
                   (bf16_t)(xc.w * mr.w + xp.w * (1.f - mr.w)) };
    bf16x4 okv = { (bf16_t)(xc.x * mk.x + xp.x * (1.f - mk.x)),
                   (bf16_t)(xc.y * mk.y + xp.y * (1.f - mk.y)),
                   (bf16_t)(xc.z * mk.z + xp.z * (1.f - mk.z)),
                   (bf16_t)(xc.w * mk.w + xp.w * (1.f - mk.w)) };
    bf16x4 ovv = { (bf16_t)(xc.x * mv.x + xp.x * (1.f - mv.x)),
                   (bf16_t)(xc.y * mv.y + xp.y * (1.f - mv.y)),
                   (bf16_t)(xc.z * mv.z + xp.z * (1.f - mv.z)),
                   (bf16_t)(xc.w * mv.w + xp.w * (1.f - mv.w)) };
    *(bf16x4*)(xr + idx) = orv;
    *(bf16x4*)(xk + idx) = okv;
    *(bf16x4*)(xv + idx) = ovv;
  }
}

// ---------------------------------------------------------------------------
// r10 GEMM core (unchanged): T3 fine-phase + T4 counted-vmcnt + T5 setprio.
// ---------------------------------------------------------------------------
#define STG(kt, la, lb, p) do {                                            \
    const char* _ga = Abase + (size_t)(kt) * 128;                          \
    const char* _gb = Bbase + (size_t)(kt) * 128;                          \
    async_copy16(_ga + (size_t)(((p) * 2 + 0) * 64 + r8) * 2048 + cbs,     \
                 (la) + ((p) * 2 + 0) * 8192 + tid * 16);                  \
    async_copy16(_ga + (size_t)(((p) * 2 + 1) * 64 + r8) * 2048 + cbs,     \
                 (la) + ((p) * 2 + 1) * 8192 + tid * 16);                  \
    async_copy16(_gb + (size_t)((p) * 64 + r8) * 2048 + cbs,               \
                 (lb) + (p) * 8192 + tid * 16);                            \
  } while (0)

#define PH1(la, lb, STMT) do {                                             \
    _Pragma("unroll")                                                      \
    for (int _j = 0; _j < 4; ++_j) {                                       \
      const char* _rb = (lb) + (wn * 64 + _j * 16 + l15) * 128;            \
      bfr[_j][0] = *(const bf16x8*)(_rb + ((quad * 16) ^ swz));            \
      bfr[_j][1] = *(const bf16x8*)(_rb + ((64 + quad * 16) ^ swz));       \
    }                                                                      \
    _Pragma("unroll")                                                      \
    for (int _i = 0; _i < 2; ++_i) {                                       \
      const char* _ra = (la) + (wm * 64 + _i * 16 + l15) * 128;            \
      afr[_i][0] = *(const bf16x8*)(_ra + ((quad * 16) ^ swz));            \
      afr[_i][1] = *(const bf16x8*)(_ra + ((64 + quad * 16) ^ swz));       \
    }                                                                      \
    STMT;                                                                  \
    asm volatile("s_waitcnt lgkmcnt(0)" ::: "memory");                     \
    __builtin_amdgcn_sched_barrier(0);                                     \
    __builtin_amdgcn_s_setprio(1);                                         \
    _Pragma("unroll")                                                      \
    for (int _k = 0; _k < 2; ++_k)                                         \
      _Pragma("unroll")                                                    \
      for (int _i = 0; _i < 2; ++_i)                                       \
        _Pragma("unroll")                                                  \
        for (int _j = 0; _j < 4; ++_j)                                     \
          acc[_i][_j] = __builtin_amdgcn_mfma_f32_16x16x32_bf16(           \
              afr[_i][_k], bfr[_j][_k], acc[_i][_j], 0, 0, 0);             \
    __builtin_amdgcn_s_setprio(0);                                         \
  } while (0)

#define PH2(la, STMT) do {                                                 \
    _Pragma("unroll")                                                      \
    for (int _i = 0; _i < 2; ++_i) {                                       \
      const char* _ra = (la) + (wm * 64 + (2 + _i) * 16 + l15) * 128;      \
      afr[_i][0] = *(const bf16x8*)(_ra + ((quad * 16) ^ swz));            \
      afr[_i][1] = *(const bf16x8*)(_ra + ((64 + quad * 16) ^ swz));       \
    }                                                                      \
    STMT;                                                                  \
    asm volatile("s_waitcnt lgkmcnt(0)" ::: "memory");                     \
    __builtin_amdgcn_sched_barrier(0);                                     \
    __builtin_amdgcn_s_setprio(1);                                         \
    _Pragma("unroll")                                                      \
    for (int _k = 0; _k < 2; ++_k)                                         \
      _Pragma("unroll")                                                    \
      for (int _i = 0; _i < 2; ++_i)                                       \
        _Pragma("unroll")                                                  \
        for (int _j = 0; _j < 4; ++_j)                                     \
          acc[2 + _i][_j] = __builtin_amdgcn_mfma_f32_16x16x32_bf16(       \
              afr[_i][_k], bfr[_j][_k], acc[2 + _i][_j], 0, 0, 0);         \
    __builtin_amdgcn_s_setprio(0);                                         \
  } while (0)

#define FENCE_BAR(N) do {                                                  \
    asm volatile("s_waitcnt vmcnt(" #N ")" ::: "memory");                  \
    __builtin_amdgcn_s_barrier();                                          \
    asm volatile("" ::: "memory");                                         \
  } while (0)

template <typename CT>
__device__ __forceinline__ void gemm_core(const bf16_t* __restrict__ A,
                                          const bf16_t* __restrict__ Bw,
                                          CT* __restrict__ C, int m0, int n0) {
  __shared__ __align__(16) bf16_t As[3][256][64];   // 96 KiB
  __shared__ __align__(16) bf16_t Bs[3][128][64];   // 48 KiB

  const int tid  = threadIdx.x;
  const int lane = tid & 63;
  const int wave = tid >> 6;
  const int wm   = wave >> 1;
  const int wn   = wave & 1;
  const int l15  = lane & 15;
  const int quad = lane >> 4;
  const int r8   = tid >> 3;
  const int cbs  = (((tid & 7) ^ (r8 & 7)) << 4);
  const int swz  = (l15 & 7) << 4;

  const char* Abase = (const char*)(A + (size_t)m0 * D_);
  const char* Bbase = (const char*)(Bw + (size_t)n0 * D_);

  char* const a0 = (char*)&As[0][0][0];
  char* const a1 = a0 + 32768;
  char* const a2 = a1 + 32768;
  char* const b0 = (char*)&Bs[0][0][0];
  char* const b1 = b0 + 16384;
  char* const b2 = b1 + 16384;

  floatx4 acc[4][4] = {};
  bf16x8 afr[2][2], bfr[4][2];

  STG(0, a0, b0, 0); STG(0, a0, b0, 1);
  STG(1, a1, b1, 0); STG(1, a1, b1, 1);
  FENCE_BAR(6);

  char *aC = a0, *aN = a1, *aF = a2;
  char *bC = b0, *bN = b1, *bF = b2;

#pragma unroll 1
  for (int t = 0; t < 14; ++t) {
    PH1(aC, bC, STG(t + 2, aF, bF, 0));
    PH2(aC,     STG(t + 2, aF, bF, 1));
    FENCE_BAR(6);
    char* x;
    x = aC; aC = aN; aN = aF; aF = x;
    x = bC; bC = bN; bN = bF; bF = x;
  }
  PH1(aC, bC, (void)0);
  PH2(aC,     (void)0);
  FENCE_BAR(0);
  PH1(aN, bN, (void)0);
  PH2(aN,     (void)0);

#pragma unroll
  for (int i = 0; i < 4; ++i) {
#pragma unroll
    for (int j = 0; j < 4; ++j) {
      int row = m0 + wm * 64 + i * 16 + quad * 4;
      int col = n0 + wn * 64 + j * 16 + l15;
      CT* Cp = C + (size_t)row * D_ + col;
#pragma unroll
      for (int r = 0; r < 4; ++r)
        Cp[(size_t)r * D_] = (CT)acc[i][j][r];
    }
  }
}

__global__ __launch_bounds__(512, 2)
void gemm3(const bf16_t* __restrict__ xr, const bf16_t* __restrict__ xk,
           const bf16_t* __restrict__ xv, const bf16_t* __restrict__ Wall,
           bf16_t* __restrict__ rbuf, bf16_t* __restrict__ kbuf, bf16_t* __restrict__ vbuf) {
  const int flat = blockIdx.x;                  // 0..767
  const int idx  = (flat & 7) * 96 + (flat >> 3);
  const int proj = idx >> 8;
  const int tt   = idx & 255;
  const int mb   = tt >> 3;
  const int nb   = tt & 7;
  const bf16_t* A  = (proj == 0) ? xr : (proj == 1) ? xk : xv;
  const bf16_t* Bw = Wall + (size_t)proj * (1 << 20);
  bf16_t* C = (proj == 0) ? rbuf : (proj == 1) ? kbuf : vbuf;
  gemm_core<bf16_t>(A, Bw, C, mb * 256, nb * 128);
}

__global__ __launch_bounds__(512, 2)
void gemm_bt(const bf16_t* __restrict__ A, const bf16_t* __restrict__ Bw,
             float* __restrict__ C) {
  const int flat = blockIdx.x;                  // 0..255
  const int idx  = (flat & 7) * 32 + (flat >> 3);
  const int mb   = idx >> 3;
  const int nb   = idx & 7;
  gemm_core<float>(A, Bw, C, mb * 256, nb * 128);
}

// ---------------------------------------------------------------------------
// bf16 chunk staging: one wave-instr covers 8 rows (8 lanes x 16 B per row);
// 4 instrs stage a 32-t x 64-ch tile (4 KB), fully coalesced.
// ---------------------------------------------------------------------------
__device__ __forceinline__ void stage_chunk_bf16(const char* gsrc, char* lds, int lane) {
  const int row = lane >> 3;            // 0..7 within group
  const int cb  = (lane & 7) * 16;
#pragma unroll
  for (int i = 0; i < 4; ++i) {
    size_t go = (size_t)(i * 8 + row) * (D_ * 2) + cb;
    async_copy16(gsrc + go, lds + i * 1024 + lane * 16);
  }
}

// ---------------------------------------------------------------------------
// r22: r19's measured config (QB=4, CLq=32, k+v LDS, (1024,4) -> 70.7us)
// with ONE change: cheaper sync primitives. r21's cross-round arithmetic
// isolated ~15us per flag-hop regardless of padding/occupancy -> the cost
// is in the primitives: each publish did threadfence + release-store (TWO
// agent-scope writeback/drains) and each poll iteration was an acquire
// load (cache-invalidate every sleep cycle). Fix:
//   * publishers: release-store ONLY (it already orders prior writes)
//   * waits: RELAXED polls (fresh value from coherence point, no
//     invalidate) + ONE acquire fence hoisted after flag observation,
//     before payload reads. Identical semantics, fraction of the cost.
// Clean A/B vs r19's 260.3 since the base config is a measured state.
// ---------------------------------------------------------------------------
__global__ __launch_bounds__(1024, 4)
void wkv_gn(const bf16_t* __restrict__ rbuf, const bf16_t* __restrict__ kbuf,
            const bf16_t* __restrict__ vbuf,
            const float* __restrict__ time_decay, const float* __restrict__ time_first,
            const float* __restrict__ gamma, const float* __restrict__ beta,
            float* __restrict__ Gtot, float* __restrict__ Atot, float* __restrict__ Btot,
            unsigned* __restrict__ flagG, unsigned* __restrict__ flagT,
            unsigned* __restrict__ cnt, float* __restrict__ psum, float* __restrict__ psq,
            bf16_t* __restrict__ normed) {
  __shared__ __align__(16) bf16_t kS[QC_][CLq * 64];   // 64 KB
  __shared__ __align__(16) bf16_t vS[QC_][CLq * 64];   // 64 KB
  __shared__ float Gs[QC_][64];                        // 4 KB
  __shared__ float As_[QC_][64];                       // 4 KB
  __shared__ float Bs_[QC_][64];                       // 4 KB
  __shared__ float predA[QB_ - 1][64];                 // 768 B
  __shared__ float predB[QB_ - 1][64];                 // 768 B
  __shared__ float redS[QC_], redQ[QC_];
  __shared__ float statsLds[2];

  const int blk  = blockIdx.x;      // 0..255
  const int bh   = blk & 63;
  const int q    = blk >> 6;        // 0..3
  const int tid  = threadIdx.x;
  const int lc   = tid >> 6;        // 0..15 local chunk (wave)
  const int lane = tid & 63;
  const int b = bh >> 4, h = bh & 15;
  const int c = h * HD_ + lane;
  const float w = -__expf(time_decay[c]);
  const float u = time_first[c];
  const float wCL  = w * (float)CLq;           // 32-step hop
  const float wBLK = w * (float)(QC_ * CLq);   // 512-step hop

  const int chunk = q * QC_ + lc;   // 0..63 global chunk
  const size_t sbase = ((size_t)b * S_ + (size_t)chunk * CLq) * D_ + h * HD_;
  const size_t gbase = sbase + lane;
  const bf16_t* rg = rbuf + gbase;
  const int pidx = bh * QB_;        // flag/payload base for this bh

  // ---- stage k,v tiles (coalesced, reused by all phases) ----
  stage_chunk_bf16((const char*)(kbuf + sbase), (char*)&kS[lc][0], lane);
  stage_chunk_bf16((const char*)(vbuf + sbase), (char*)&vS[lc][0], lane);
  __builtin_amdgcn_s_waitcnt(0);    // own-wave loads only; no barrier needed

  // ---- Phase A: chunk-local b-scan from -inf (k from LDS) ----
  {
    float g = -1e38f;
#pragma unroll
    for (int t = 0; t < CLq; ++t) {
      float kt = (float)kS[lc][t * 64 + lane];
      float ww = g + w;
      float d2 = ww - kt;
      float em = __expf(-fabsf(d2));
      float e1b = (d2 >= 0.0f) ? 1.0f : em;
      float e2b = (d2 >= 0.0f) ? em : 1.0f;
      g = fmaxf(ww, kt) + __logf(e1b + e2b + 1e-8f);
    }
    Gs[lc][lane] = g;
  }
  __syncthreads();

  // exclusive local prefix P; wave15 publishes block total
  float P = -1e38f;
  for (int cc = 0; cc < lc; ++cc) {
    float gv = Gs[cc][lane];
    float b1 = P + wCL;
    float dd = b1 - gv;
    float em = __expf(-fabsf(dd));
    P = fmaxf(b1, gv) + __logf(1.0f + em);
  }
  if (lc == QC_ - 1) {
    float gv = Gs[QC_ - 1][lane];
    float b1 = P + wCL;
    float dd = b1 - gv;
    float em = __expf(-fabsf(dd));
    float gt = fmaxf(b1, gv) + __logf(1.0f + em);
    *((volatile float*)(Gtot + (pidx + q) * 64 + lane)) = gt;
    // release store orders the payload write above; no explicit fence
    if (lane == 0)
      __hip_atomic_store(&flagG[(pidx + q) * FPAD], 1u, __ATOMIC_RELEASE, __HIP_MEMORY_SCOPE_AGENT);
  }

  // gather predecessor G totals: wave0 only; lane0 relaxed-polls;
  // one acquire fence after observation; coalesced payload reads
  if (lc == 0) {
    for (int j = 0; j < q; ++j) {
      if (lane == 0)
        while (__hip_atomic_load(&flagG[(pidx + j) * FPAD], __ATOMIC_RELAXED, __HIP_MEMORY_SCOPE_AGENT) == 0u)
          __builtin_amdgcn_s_sleep(32);
    }
    if (q > 0) __builtin_amdgcn_fence(__ATOMIC_ACQUIRE, "agent");
    for (int j = 0; j < q; ++j)
      predA[j][lane] = *((volatile const float*)(Gtot + (pidx + j) * 64 + lane));
  }
  __syncthreads();

  float b_in = -1e38f;
  for (int j = 0; j < q; ++j) {
    float gt = predA[j][lane];
    float b1 = b_in + wBLK;
    float dd = b1 - gt;
    float em = __expf(-fabsf(dd));
    b_in = fmaxf(b1, gt) + __logf(1.0f + em);
  }
  float bst_in;
  {
    float b1 = b_in + wCL * (float)lc;
    float dd = b1 - P;
    float em = __expf(-fabsf(dd));
    bst_in = fmaxf(b1, P) + __logf(1.0f + em);
  }

  // ---- Phase B: a-transfer scan (k,v from LDS) ----
  {
    float a = 0.0f, Ap = 1.0f;
    float bst = bst_in;
#pragma unroll
    for (int t = 0; t < CLq; ++t) {
      float kt = (float)kS[lc][t * 64 + lane];
      float vt = (float)vS[lc][t * 64 + lane];
      float ww = bst + w;
      float d2 = ww - kt;
      float em = __expf(-fabsf(d2));
      float e1b = (d2 >= 0.0f) ? 1.0f : em;
      float e2b = (d2 >= 0.0f) ? em : 1.0f;
      a  = e1b * a + e2b * vt;
      Ap = Ap * e1b;
      bst = fmaxf(ww, kt) + __logf(e1b + e2b + 1e-8f);
    }
    As_[lc][lane] = Ap;
    Bs_[lc][lane] = a;
  }
  __syncthreads();

  float Aex = 1.0f, Bex = 0.0f;
  for (int cc = 0; cc < lc; ++cc) {
    float Ac = As_[cc][lane], Bc = Bs_[cc][lane];
    Aex = Ac * Aex;
    Bex = Ac * Bex + Bc;
  }
  if (lc == QC_ - 1) {
    float Ac = As_[QC_ - 1][lane], Bc = Bs_[QC_ - 1][lane];
    float At = Ac * Aex;
    float Bt = Ac * Bex + Bc;
    *((volatile float*)(Atot + (pidx + q) * 64 + lane)) = At;
    *((volatile float*)(Btot + (pidx + q) * 64 + lane)) = Bt;
    if (lane == 0)
      __hip_atomic_store(&flagT[(pidx + q) * FPAD], 1u, __ATOMIC_RELEASE, __HIP_MEMORY_SCOPE_AGENT);
  }

  if (lc == 0) {
    for (int j = 0; j < q; ++j) {
      if (lane == 0)
        while (__hip_atomic_load(&flagT[(pidx + j) * FPAD], __ATOMIC_RELAXED, __HIP_MEMORY_SCOPE_AGENT) == 0u)
          __builtin_amdgcn_s_sleep(32);
    }
    if (q > 0) __builtin_amdgcn_fence(__ATOMIC_ACQUIRE, "agent");
    for (int j = 0; j < q; ++j) {
      predA[j][lane] = *((volatile const float*)(Atot + (pidx + j) * 64 + lane));
      predB[j][lane] = *((volatile const float*)(Btot + (pidx + j) * 64 + lane));
    }
  }
  __syncthreads();

  float a_in = 0.0f;
  for (int j = 0; j < q; ++j)
    a_in = predA[j][lane] * a_in + predB[j][lane];
  const float a0 = Aex * a_in + Bex;

  // ---- Phase C: exact reference steps; o2 in registers; GN partials ----
  float o2[CLq];
  {
    float a = a0, bst = bst_in;
    float sum = 0.0f, sq = 0.0f;
#pragma unroll
    for (int t = 0; t < CLq; ++t) {
      float kt = (float)kS[lc][t * 64 + lane];
      float vt = (float)vS[lc][t * 64 + lane];
      float rt = (float)rg[(size_t)t * D_];
      float wk = kt + u;
      float d1 = bst - wk;
      float em1 = __expf(-fabsf(d1));
      float e1 = (d1 >= 0.0f) ? 1.0f : em1;
      float e2 = (d1 >= 0.0f) ? em1 : 1.0f;
      float out = __fdividef(e1 * a + e2 * vt, e1 + e2 + 1e-8f);

      float ww = bst + w;
      float d2 = ww - kt;
      float em2 = __expf(-fabsf(d2));
      float e1b = (d2 >= 0.0f) ? 1.0f : em2;
      float e2b = (d2 >= 0.0f) ? em2 : 1.0f;
      a   = e1b * a + e2b * vt;
      bst = fmaxf(ww, kt) + __logf(e1b + e2b + 1e-8f);

      float sig = __fdividef(1.0f, 1.0f + __expf(-rt));
      float o = sig * out;
      o2[t] = o;
      sum += o; sq += o * o;
    }
#pragma unroll
    for (int off = 32; off > 0; off >>= 1) {
      sum += __shfl_down(sum, off);
      sq  += __shfl_down(sq, off);
    }
    if (lane == 0) { redS[lc] = sum; redQ[lc] = sq; }
  }
  __syncthreads();
  if (tid == 0) {
    float s = 0.0f, qq = 0.0f;
#pragma unroll
    for (int i = 0; i < QC_; ++i) { s += redS[i]; qq += redQ[i]; }
    atomicAdd(&psum[bh * FPAD], s);
    atomicAdd(&psq[bh * FPAD], qq);
    __builtin_amdgcn_fence(__ATOMIC_RELEASE, "agent");  // order adds before cnt
    atomicAdd(&cnt[bh * FPAD], 1u);
    while (__hip_atomic_load(&cnt[bh * FPAD], __ATOMIC_RELAXED, __HIP_MEMORY_SCOPE_AGENT) < (unsigned)QB_)
      __builtin_amdgcn_s_sleep(32);
    __builtin_amdgcn_fence(__ATOMIC_ACQUIRE, "agent");
    float sA = *((volatile const float*)&psum[bh * FPAD]);
    float qA = *((volatile const float*)&psq[bh * FPAD]);
    const float n = (float)(S_ * HD_);
    float mean = sA / n;
    float var  = qA / n - mean * mean;
    statsLds[0] = mean;
    statsLds[1] = rsqrtf(var + 1e-5f);
  }
  __syncthreads();

  // ---- Phase D: GroupNorm apply from registers ----
  {
    const float mean = statsLds[0];
    const float gm   = gamma[c] * statsLds[1];
    const float bt   = beta[c];
    bf16_t* og = normed + gbase;
#pragma unroll
    for (int t = 0; t < CLq; ++t)
      og[(size_t)t * D_] = (bf16_t)((o2[t] - mean) * gm + bt);
  }
}

// ---------------------------------------------------------------------------
extern "C" void kernel_launch(void* const* d_in, const int* in_sizes, int n_in,
                              void* d_out, int out_size, void* d_ws, size_t ws_size,
                              hipStream_t stream) {
  const float* x     = (const float*)d_in[0];
  const float* tmr   = (const float*)d_in[1];
  const float* tmk   = (const float*)d_in[2];
  const float* tmv   = (const float*)d_in[3];
  const float* Wr    = (const float*)d_in[4];
  const float* Wk    = (const float*)d_in[5];
  const float* Wv    = (const float*)d_in[6];
  const float* Wo    = (const float*)d_in[7];
  const float* td    = (const float*)d_in[8];
  const float* tf    = (const float*)d_in[9];
  const float* gamma = (const float*)d_in[10];
  const float* beta  = (const float*)d_in[11];

  char* ws = (char*)d_ws;
  const size_t MB = 1024 * 1024;
  bf16_t* W_bf    = (bf16_t*)(ws + 0 * MB);    // Wr,Wk,Wv,Wo bf16, 8 MB
  bf16_t* Wo_bf   = (bf16_t*)(ws + 6 * MB);
  bf16_t* xr      = (bf16_t*)(ws + 8 * MB);    // 16 MB each
  bf16_t* xk      = (bf16_t*)(ws + 24 * MB);
  bf16_t* xv      = (bf16_t*)(ws + 40 * MB);
  // scan sync/scratch in dead xk space (28 MB +); zeroed AFTER gemm3.
  // All flags/counters cacheline-padded (FPAD=16 u32 = 64 B).
  unsigned* flagG = (unsigned*)(ws + 28 * MB);          // 256*64B = 16 KB
  unsigned* flagT = (unsigned*)(ws + 28 * MB + 16384);  // 16 KB
  unsigned* cnt   = (unsigned*)(ws + 28 * MB + 32768);  // 64*64B = 4 KB
  float*    psum  = (float*)(ws + 28 * MB + 40960);     // 4 KB (padded)
  float*    psq   = (float*)(ws + 28 * MB + 45056);     // 4 KB (padded)
  float*    Gtot  = (float*)(ws + 28 * MB + 64 * 1024); // 256*64 f32 each
  float*    Atot  = Gtot + 256 * 64;
  float*    Btot  = Atot + 256 * 64;
  bf16_t* rbuf    = (bf16_t*)(ws + 56 * MB);   // 16 MB each, bf16
  bf16_t* kbuf    = (bf16_t*)(ws + 72 * MB);
  bf16_t* vbuf    = (bf16_t*)(ws + 88 * MB);
  bf16_t* normed  = xr;                        // xr dead after gemm3

  float* outp = (float*)d_out;

  pre_kernel<<<(3 * 1024 * 1024) / 256, 256, 0, stream>>>(
      Wr, Wk, Wv, Wo, W_bf, x, tmr, tmk, tmv, xr, xk, xv);

  gemm3<<<768, 512, 0, stream>>>(xr, xk, xv, W_bf, rbuf, kbuf, vbuf);

  hipMemsetAsync(ws + 28 * MB, 0, 49152, stream);  // padded flags/cnt/psum/psq

  wkv_gn<<<256, 1024, 0, stream>>>(rbuf, kbuf, vbuf, td, tf, gamma, beta,
                                   Gtot, Atot, Btot, flagG, flagT, cnt,
                                   psum, psq, normed);

  gemm_bt<<<256, 512, 0, stream>>>(normed, Wo_bf, outp);
}